// Round 12
// baseline (199.676 us; speedup 1.0000x reference)
//
#include <hip/hip_runtime.h>

#define N_SAMPLES 65536
#define C_CLASSES 256
#define D_DIM     1024
#define ALPHA_C   1.0f
#define GAMMA_C   0.01f
#define LCAP      512      // per-half-class list capacity (mean 128, sd 11)
#define NW        16       // waves per block (1024 threads)

// ---------------------------------------------------------------------------
// prep kernel, 336 blocks x 256:
//   bid [0,64)   : sqv[c] = ||cluster[c]||^2   (4 classes/block, 1 wave each)
//   bid [64,80)  : T[d] = sum_c cluster[c][d]  (64-dim slice per block)
//   bid [80,336) : zero out_cluster (atomicAdd target)
__global__ __launch_bounds__(256) void prep_kernel(
    const float* __restrict__ cluster,
    float* __restrict__ sqv_g,      // 256 floats
    float* __restrict__ T_g,        // 1024 floats
    float* __restrict__ out_cluster)
{
    int bid = blockIdx.x, t = threadIdx.x;
    int w = t >> 6, lane = t & 63;

    if (bid < 64) {
        int c = bid * 4 + w;
        const float4* row = (const float4*)(cluster + (size_t)c * D_DIM);
        float sq = 0.f;
#pragma unroll
        for (int j = 0; j < 4; ++j) {
            float4 v = row[j * 64 + lane];
            sq += v.x * v.x + v.y * v.y + v.z * v.z + v.w * v.w;
        }
#pragma unroll
        for (int m = 32; m >= 1; m >>= 1) sq += __shfl_xor(sq, m, 64);
        if (lane == 0) sqv_g[c] = sq;
        return;
    }
    if (bid < 80) {
        __shared__ float part[4][64];
        int dimbase = (bid - 64) * 64;
        const float* base = cluster + dimbase + lane;
        float s = 0.f;
#pragma unroll 4
        for (int i = 0; i < 64; ++i) {
            int r = w * 64 + i;
            s += base[(size_t)r * D_DIM];
        }
        part[w][lane] = s;
        __syncthreads();
        if (w == 0)
            T_g[dimbase + lane] = part[0][lane] + part[1][lane] +
                                  part[2][lane] + part[3][lane];
        return;
    }
    {
        int b = bid - 80;   // 0..255
        ((float4*)out_cluster)[b * 256 + t] = make_float4(0.f, 0.f, 0.f, 0.f);
    }
}

// ---------------------------------------------------------------------------
// main kernel, 512 blocks x 1024 (2 blocks/CU -> 32 waves/CU). Block = (class,
// half): compacts its half of the label range, computes denom from the prep
// tables (O(D) via relu-free algebra), streams its ~128 feature rows with the
// R10-proven depth-2 rotation, then combines dsum and atomicAdds the output.
__global__ __launch_bounds__(1024, 8) void main_kernel(
    const float* __restrict__ features,
    const int*   __restrict__ labels, int lab_stride,
    const float* __restrict__ cluster,
    const float* __restrict__ cls_w,
    const float* __restrict__ sqv_g,
    const float* __restrict__ T_g,
    float* __restrict__ loss_out,
    float* __restrict__ out_cluster)
{
    __shared__ int   list_[LCAP];                  // 2 KB
    __shared__ int   s_cnt;
    __shared__ float s_denom;
    __shared__ alignas(16) float cc[D_DIM];        // 4 KB (my cluster row)
    __shared__ alignas(16) float comb[NW][D_DIM];  // 64 KB (wave dsum combine)

    const int bid = blockIdx.x;
    const int c = bid >> 1, h = bid & 1;
    const int t = threadIdx.x;
    const int w = t >> 6, lane = t & 63;

    if (t == 0) s_cnt = 0;
    if (t < 256) ((float4*)cc)[t] = ((const float4*)(cluster + (size_t)c * D_DIM))[t];
    __syncthreads();
    const float4* cc4 = (const float4*)cc;

    // ---------------- A: ballot compaction of this HALF's samples -----------
#define COMPACT4(m0, m1, m2, m3, s0)                                         \
    {                                                                        \
        unsigned long long b0 = __ballot(m0), b1 = __ballot(m1);             \
        unsigned long long b2 = __ballot(m2), b3 = __ballot(m3);             \
        int tot = __popcll(b0) + __popcll(b1) + __popcll(b2) + __popcll(b3); \
        if (tot) {                                                           \
            int bb = 0;                                                      \
            if (lane == 0) bb = atomicAdd(&s_cnt, tot);                      \
            bb = __shfl(bb, 0, 64);                                          \
            unsigned long long lm = (1ull << lane) - 1ull;                   \
            int p = bb + __popcll(b0 & lm) + __popcll(b1 & lm)               \
                       + __popcll(b2 & lm) + __popcll(b3 & lm);              \
            if (m0) { if (p < LCAP) list_[p] = (s0);     ++p; }              \
            if (m1) { if (p < LCAP) list_[p] = (s0) + 1; ++p; }              \
            if (m2) { if (p < LCAP) list_[p] = (s0) + 2; ++p; }              \
            if (m3) { if (p < LCAP) list_[p] = (s0) + 3; ++p; }              \
        }                                                                    \
    }

    const int ch0 = h * 128, ch1 = ch0 + 128;      // this half's 128 chunks
    if (lab_stride == 2) {            // int64 labels: int4 = 2 labels (x,z low)
        const int4* lab4 = (const int4*)labels;
        for (int chunk = ch0 + w; chunk < ch1; chunk += NW) {
            int s0 = chunk * 256 + lane * 4;
            int4 v0 = lab4[(s0 >> 1)];
            int4 v1 = lab4[(s0 >> 1) + 1];
            COMPACT4(v0.x == c, v0.z == c, v1.x == c, v1.z == c, s0);
        }
    } else {                          // int32 labels: int4 = 4 labels
        const int4* lab4 = (const int4*)labels;
        for (int chunk = ch0 + w; chunk < ch1; chunk += NW) {
            int s0 = chunk * 256 + lane * 4;
            int4 v = lab4[s0 >> 2];
            COMPACT4(v.x == c, v.y == c, v.z == c, v.w == c, s0);
        }
    }
#undef COMPACT4
    __syncthreads();
    const int cnt = (s_cnt > LCAP) ? LCAP : s_cnt;

    // ---------------- B: denom from prep tables (wave 0, O(D)) --------------
    if (w == 0) {
        const float4* T4 = (const float4*)T_g;
        float dt = 0.f;
#pragma unroll
        for (int j = 0; j < 4; ++j) {
            float4 tv = T4[j * 64 + lane];
            float4 av = cc4[j * 64 + lane];
            dt += tv.x * av.x + tv.y * av.y + tv.z * av.z + tv.w * av.w;
        }
        float4 sv = ((const float4*)sqv_g)[lane];
        float S = sv.x + sv.y + sv.z + sv.w;
#pragma unroll
        for (int m = 32; m >= 1; m >>= 1) {
            dt += __shfl_xor(dt, m, 64);
            S  += __shfl_xor(S,  m, 64);
        }
        if (lane == 0)
            s_denom = 256.f * sqv_g[c] + S - 2.f * dt + ALPHA_C;
    }
    __syncthreads();
    const float inv_dnm = 1.0f / s_denom;

    // ---------------- C: stream this half's feature rows --------------------
    float4 ck[4];
#pragma unroll
    for (int j = 0; j < 4; ++j) ck[j] = cc4[j * 64 + lane];

    float4 dsum[4];
#pragma unroll
    for (int j = 0; j < 4; ++j) dsum[j] = make_float4(0.f, 0.f, 0.f, 0.f);

    int niter = (cnt > w) ? ((cnt - w - 1) / NW + 1) : 0;   // wave w: w, w+16, ...

#define LOADROW(buf, idx)                                                    \
    {                                                                        \
        const float4* f_ = (const float4*)(features + (size_t)(idx) * D_DIM);\
        _Pragma("unroll")                                                    \
        for (int j = 0; j < 4; ++j) buf[j] = f_[j * 64 + lane];              \
    }
#define COMPUTE(buf, idx)                                                    \
    {                                                                        \
        float nume = 0.f;                                                    \
        _Pragma("unroll")                                                    \
        for (int j = 0; j < 4; ++j) {                                        \
            float dx = buf[j].x - ck[j].x, dy = buf[j].y - ck[j].y;          \
            float dz = buf[j].z - ck[j].z, dw = buf[j].w - ck[j].w;          \
            dsum[j].x += dx; dsum[j].y += dy;                                \
            dsum[j].z += dz; dsum[j].w += dw;                                \
            nume += dx * dx + dy * dy + dz * dz + dw * dw;                   \
        }                                                                    \
        _Pragma("unroll")                                                    \
        for (int m = 32; m >= 1; m >>= 1) nume += __shfl_xor(nume, m, 64);   \
        if (lane == 0) loss_out[idx] = nume * inv_dnm;                       \
    }

    float4 bufA[4], bufB[4];
    int ia = (0 < niter) ? list_[w] : -1;
    int ib = (1 < niter) ? list_[w + NW] : -1;
    if (ia >= 0) LOADROW(bufA, ia);
    int n = 0;
    while (n + 1 < niter) {
        LOADROW(bufB, ib);                                   // prefetch n+1
        int ic = (n + 2 < niter) ? list_[w + (n + 2) * NW] : -1;
        COMPUTE(bufA, ia);                                   // compute n
        if (ic >= 0) LOADROW(bufA, ic);                      // prefetch n+2
        int id = (n + 3 < niter) ? list_[w + (n + 3) * NW] : -1;
        COMPUTE(bufB, ib);                                   // compute n+1
        ia = ic; ib = id; n += 2;
    }
    if (n < niter) COMPUTE(bufA, ia);                        // odd tail
#undef LOADROW
#undef COMPUTE

    // ---------------- D: combine 16 waves, atomicAdd into out ---------------
    {
        float4* cwv = (float4*)comb[w];
#pragma unroll
        for (int j = 0; j < 4; ++j) cwv[j * 64 + lane] = dsum[j];
    }
    __syncthreads();
    if (t < 256) {
        float sc_ = GAMMA_C * cls_w[c] * inv_dnm;
        float4 s = make_float4(0.f, 0.f, 0.f, 0.f);
#pragma unroll
        for (int r = 0; r < NW; ++r) {
            float4 u = ((const float4*)comb[r])[t];
            s.x += u.x; s.y += u.y; s.z += u.z; s.w += u.w;
        }
        float4 cv = cc4[t];
        float ax = (h == 0 ? cv.x : 0.f) - sc_ * s.x;
        float ay = (h == 0 ? cv.y : 0.f) - sc_ * s.y;
        float az = (h == 0 ? cv.z : 0.f) - sc_ * s.z;
        float aw = (h == 0 ? cv.w : 0.f) - sc_ * s.w;
        float* outc = out_cluster + (size_t)c * D_DIM + 4 * t;
        atomicAdd(outc + 0, ax);
        atomicAdd(outc + 1, ay);
        atomicAdd(outc + 2, az);
        atomicAdd(outc + 3, aw);
    }
}

// ---------------------------------------------------------------------------
extern "C" void kernel_launch(void* const* d_in, const int* in_sizes, int n_in,
                              void* d_out, int out_size, void* d_ws, size_t ws_size,
                              hipStream_t stream) {
    const float* features = (const float*)d_in[0];
    const int*   labels   = (const int*)d_in[1];
    const float* cluster  = (const float*)d_in[2];
    const float* cls_w    = (const float*)d_in[3];
    int lab_stride = in_sizes[1] / N_SAMPLES;   // 1 if int32 words, 2 if int64 words
    if (lab_stride < 1) lab_stride = 1;

    float* loss_out    = (float*)d_out;                 // N floats
    float* out_cluster = (float*)d_out + N_SAMPLES;     // C*D floats

    char* ws = (char*)d_ws;
    float* sqv_g = (float*)(ws);            // 256 f32
    float* T_g   = (float*)(ws + 4096);     // 1024 f32

    prep_kernel<<<336, 256, 0, stream>>>(cluster, sqv_g, T_g, out_cluster);
    main_kernel<<<2 * C_CLASSES, 1024, 0, stream>>>(features, labels, lab_stride,
                                                    cluster, cls_w, sqv_g, T_g,
                                                    loss_out, out_cluster);
}

// Round 13
// 86.716 us; speedup vs baseline: 2.3026x; 2.3026x over previous
//
#include <hip/hip_runtime.h>

#define N_SAMPLES 65536
#define C_CLASSES 256
#define D_DIM     1024
#define ALPHA_C   1.0f
#define GAMMA_C   0.01f
#define LCAP      1024     // per-class index list capacity (mean 256, sd 16)
#define NW        16       // waves per block (1024 threads)

// One block per class, 1024 threads (16 waves), single dispatch (R10 base).
// Stream phase uses a DEPTH-4 rotation: each wave keeps 4 independent 1 KB
// row buffers in flight (loads issued 4 iterations ahead) to cover the ~900cy
// HBM latency at 4 waves/SIMD. No global stores inside the loop (nume parked
// in LDS; loss scattered once at the end).
__global__ __launch_bounds__(1024, 1) void fused_kernel(
    const float* __restrict__ features,
    const int*   __restrict__ labels, int lab_stride,
    const float* __restrict__ cluster,
    const float* __restrict__ cls_w,
    float* __restrict__ loss_out,
    float* __restrict__ out_cluster)
{
    __shared__ int   list_[LCAP];                  // 4 KB
    __shared__ float nume_lds[LCAP];               // 4 KB
    __shared__ int   s_cnt;
    __shared__ float s_denom;
    __shared__ alignas(16) float cc[D_DIM];        // 4 KB (my cluster row)
    __shared__ float sqv[C_CLASSES];               // 1 KB
    __shared__ float dotv[C_CLASSES];              // 1 KB
    __shared__ alignas(16) float comb[NW][D_DIM];  // 64 KB (wave dsum combine)

    const int c = blockIdx.x;
    const int t = threadIdx.x;
    const int w = t >> 6, lane = t & 63;

    if (t == 0) s_cnt = 0;
    if (t < 256) ((float4*)cc)[t] = ((const float4*)(cluster + (size_t)c * D_DIM))[t];
    __syncthreads();
    const float4* cc4 = (const float4*)cc;

    // ---------------- A: ballot compaction (all 16 waves) -------------------
#define COMPACT4(m0, m1, m2, m3, s0)                                         \
    {                                                                        \
        unsigned long long b0 = __ballot(m0), b1 = __ballot(m1);             \
        unsigned long long b2 = __ballot(m2), b3 = __ballot(m3);             \
        int tot = __popcll(b0) + __popcll(b1) + __popcll(b2) + __popcll(b3); \
        if (tot) {                                                           \
            int bb = 0;                                                      \
            if (lane == 0) bb = atomicAdd(&s_cnt, tot);                      \
            bb = __shfl(bb, 0, 64);                                          \
            unsigned long long lm = (1ull << lane) - 1ull;                   \
            int p = bb + __popcll(b0 & lm) + __popcll(b1 & lm)               \
                       + __popcll(b2 & lm) + __popcll(b3 & lm);              \
            if (m0) { if (p < LCAP) list_[p] = (s0);     ++p; }              \
            if (m1) { if (p < LCAP) list_[p] = (s0) + 1; ++p; }              \
            if (m2) { if (p < LCAP) list_[p] = (s0) + 2; ++p; }              \
            if (m3) { if (p < LCAP) list_[p] = (s0) + 3; ++p; }              \
        }                                                                    \
    }

    if (lab_stride == 2) {            // int64 labels: int4 = 2 labels (x,z low)
        const int4* lab4 = (const int4*)labels;
        for (int iter = 0; iter < 16; ++iter) {
            int chunk = iter * NW + w;           // 0..255 chunks of 256 samples
            int s0 = chunk * 256 + lane * 4;
            int4 v0 = lab4[(s0 >> 1)];
            int4 v1 = lab4[(s0 >> 1) + 1];
            COMPACT4(v0.x == c, v0.z == c, v1.x == c, v1.z == c, s0);
        }
    } else {                          // int32 labels: int4 = 4 labels
        const int4* lab4 = (const int4*)labels;
        for (int iter = 0; iter < 16; ++iter) {
            int chunk = iter * NW + w;
            int s0 = chunk * 256 + lane * 4;
            int4 v = lab4[s0 >> 2];
            COMPACT4(v.x == c, v.y == c, v.z == c, v.w == c, s0);
        }
    }
#undef COMPACT4
    __syncthreads();
    const int cnt = (s_cnt > LCAP) ? LCAP : s_cnt;

    // ---------------- B: denom table (all 16 waves, 16 rows each) -----------
    for (int r = w; r < C_CLASSES; r += NW) {
        const float4* row = (const float4*)(cluster + (size_t)r * D_DIM);
        float sq = 0.f, dt = 0.f;
#pragma unroll
        for (int j = 0; j < 4; ++j) {
            float4 v = row[j * 64 + lane];
            float4 a = cc4[j * 64 + lane];
            sq += v.x * v.x + v.y * v.y + v.z * v.z + v.w * v.w;
            dt += v.x * a.x + v.y * a.y + v.z * a.z + v.w * a.w;
        }
#pragma unroll
        for (int m = 32; m >= 1; m >>= 1) {
            sq += __shfl_xor(sq, m, 64);
            dt += __shfl_xor(dt, m, 64);
        }
        if (lane == 0) { sqv[r] = sq; dotv[r] = dt; }
    }
    __syncthreads();

    if (t < 64) {
        float sqc = sqv[c];
        float s = 0.f;
#pragma unroll
        for (int jj = 0; jj < 4; ++jj) {
            int j = jj * 64 + lane;
            float p = sqc + sqv[j] - 2.f * dotv[j];
            s += (p > 0.f ? p : 0.f);
        }
#pragma unroll
        for (int m = 32; m >= 1; m >>= 1) s += __shfl_xor(s, m, 64);
        if (lane == 0) s_denom = s + ALPHA_C;
    }
    __syncthreads();
    const float inv_dnm = 1.0f / s_denom;

    // ---------------- C: stream feature rows, depth-4 rotation --------------
    float4 ck[4];
#pragma unroll
    for (int j = 0; j < 4; ++j) ck[j] = cc4[j * 64 + lane];

    float4 dsum[4];
#pragma unroll
    for (int j = 0; j < 4; ++j) dsum[j] = make_float4(0.f, 0.f, 0.f, 0.f);

    const int niter = (cnt > w) ? ((cnt - w - 1) / NW + 1) : 0;   // w, w+16, ...

#define LOADROW(buf, idx)                                                    \
    {                                                                        \
        const float4* f_ = (const float4*)(features + (size_t)(idx) * D_DIM);\
        _Pragma("unroll")                                                    \
        for (int j = 0; j < 4; ++j) buf[j] = f_[j * 64 + lane];              \
    }
#define COMPUTE(buf, pos)                                                    \
    {                                                                        \
        float nume = 0.f;                                                    \
        _Pragma("unroll")                                                    \
        for (int j = 0; j < 4; ++j) {                                        \
            float dx = buf[j].x - ck[j].x, dy = buf[j].y - ck[j].y;          \
            float dz = buf[j].z - ck[j].z, dw = buf[j].w - ck[j].w;          \
            dsum[j].x += dx; dsum[j].y += dy;                                \
            dsum[j].z += dz; dsum[j].w += dw;                                \
            nume += dx * dx + dy * dy + dz * dz + dw * dw;                   \
        }                                                                    \
        _Pragma("unroll")                                                    \
        for (int m = 32; m >= 1; m >>= 1) nume += __shfl_xor(nume, m, 64);   \
        if (lane == 0) nume_lds[pos] = nume;                                 \
    }
#define STAGE(buf, k_)                                                       \
    {                                                                        \
        int nn = n + (k_);                                                   \
        if (nn < niter) {                                                    \
            COMPUTE(buf, w + nn * NW);                                       \
            int nf = nn + 4;                                                 \
            if (nf < niter) { int ii = list_[w + nf * NW]; LOADROW(buf, ii); } \
        }                                                                    \
    }

    float4 b0[4], b1[4], b2[4], b3[4];
    if (0 < niter) { int ii = list_[w];          LOADROW(b0, ii); }
    if (1 < niter) { int ii = list_[w + NW];     LOADROW(b1, ii); }
    if (2 < niter) { int ii = list_[w + 2 * NW]; LOADROW(b2, ii); }
    if (3 < niter) { int ii = list_[w + 3 * NW]; LOADROW(b3, ii); }

    for (int n = 0; n < niter; n += 4) {
        STAGE(b0, 0);
        STAGE(b1, 1);
        STAGE(b2, 2);
        STAGE(b3, 3);
    }
#undef LOADROW
#undef COMPUTE
#undef STAGE

    // park dsum in LDS
    {
        float4* cwv = (float4*)comb[w];
#pragma unroll
        for (int j = 0; j < 4; ++j) cwv[j * 64 + lane] = dsum[j];
    }
    __syncthreads();

    // ---------------- D: loss scatter + combine + direct store --------------
    for (int j = t; j < cnt; j += 1024)
        loss_out[list_[j]] = nume_lds[j] * inv_dnm;

    if (t < 256) {
        float sc_ = GAMMA_C * cls_w[c] * inv_dnm;
        float4 s = make_float4(0.f, 0.f, 0.f, 0.f);
#pragma unroll
        for (int r = 0; r < NW; ++r) {
            float4 u = ((const float4*)comb[r])[t];
            s.x += u.x; s.y += u.y; s.z += u.z; s.w += u.w;
        }
        float4 cv = cc4[t];
        float4 o;
        o.x = cv.x - sc_ * s.x;
        o.y = cv.y - sc_ * s.y;
        o.z = cv.z - sc_ * s.z;
        o.w = cv.w - sc_ * s.w;
        ((float4*)(out_cluster + (size_t)c * D_DIM))[t] = o;
    }
}

// ---------------------------------------------------------------------------
extern "C" void kernel_launch(void* const* d_in, const int* in_sizes, int n_in,
                              void* d_out, int out_size, void* d_ws, size_t ws_size,
                              hipStream_t stream) {
    const float* features = (const float*)d_in[0];
    const int*   labels   = (const int*)d_in[1];
    const float* cluster  = (const float*)d_in[2];
    const float* cls_w    = (const float*)d_in[3];
    int lab_stride = in_sizes[1] / N_SAMPLES;   // 1 if int32 words, 2 if int64 words
    if (lab_stride < 1) lab_stride = 1;

    float* loss_out    = (float*)d_out;                 // N floats
    float* out_cluster = (float*)d_out + N_SAMPLES;     // C*D floats

    fused_kernel<<<C_CLASSES, 1024, 0, stream>>>(features, labels, lab_stride,
                                                 cluster, cls_w, loss_out, out_cluster);
}

// Round 14
// 78.538 us; speedup vs baseline: 2.5424x; 1.1041x over previous
//
#include <hip/hip_runtime.h>

#define N_SAMPLES 65536
#define C_CLASSES 256
#define D_DIM     1024
#define ALPHA_C   1.0f
#define GAMMA_C   0.01f
#define LCAP      1024     // per-class index list capacity (mean 256, sd 16)
#define NW        16       // waves per block (1024 threads)

// One block per class, 1024 threads (16 waves), single dispatch.
// Order: compaction -> stream (nume parked in LDS, depth-2 rotation, R10-
// proven) -> per-wave denom tail (relu-free algebra: T = colsum, S = frob^2;
// NO per-row reductions, NO barrier before it -> hides in wave stagger) ->
// single barrier -> finish (denom scalar, loss scatter, direct store).
__global__ __launch_bounds__(1024, 1) void fused_kernel(
    const float* __restrict__ features,
    const int*   __restrict__ labels, int lab_stride,
    const float* __restrict__ cluster,
    const float* __restrict__ cls_w,
    float* __restrict__ loss_out,
    float* __restrict__ out_cluster)
{
    __shared__ int   list_[LCAP];                  // 4 KB
    __shared__ float nume_lds[LCAP];               // 4 KB
    __shared__ int   s_cnt;
    __shared__ float s_denom;
    __shared__ float s_S;
    __shared__ alignas(16) float cc[D_DIM];        // 4 KB (my cluster row)
    __shared__ alignas(16) float Tlds[D_DIM];      // 4 KB (colsum accumulator)
    __shared__ alignas(16) float comb[NW][D_DIM];  // 64 KB (wave dsum combine)

    const int c = blockIdx.x;
    const int t = threadIdx.x;
    const int w = t >> 6, lane = t & 63;

    if (t == 0) { s_cnt = 0; s_S = 0.f; }
    if (t < 256) {
        ((float4*)cc)[t] = ((const float4*)(cluster + (size_t)c * D_DIM))[t];
        ((float4*)Tlds)[t] = make_float4(0.f, 0.f, 0.f, 0.f);
    }
    __syncthreads();
    const float4* cc4 = (const float4*)cc;

    // ---------------- A: ballot compaction (all 16 waves) -------------------
#define COMPACT4(m0, m1, m2, m3, s0)                                         \
    {                                                                        \
        unsigned long long b0 = __ballot(m0), b1 = __ballot(m1);             \
        unsigned long long b2 = __ballot(m2), b3 = __ballot(m3);             \
        int tot = __popcll(b0) + __popcll(b1) + __popcll(b2) + __popcll(b3); \
        if (tot) {                                                           \
            int bb = 0;                                                      \
            if (lane == 0) bb = atomicAdd(&s_cnt, tot);                      \
            bb = __shfl(bb, 0, 64);                                          \
            unsigned long long lm = (1ull << lane) - 1ull;                   \
            int p = bb + __popcll(b0 & lm) + __popcll(b1 & lm)               \
                       + __popcll(b2 & lm) + __popcll(b3 & lm);              \
            if (m0) { if (p < LCAP) list_[p] = (s0);     ++p; }              \
            if (m1) { if (p < LCAP) list_[p] = (s0) + 1; ++p; }              \
            if (m2) { if (p < LCAP) list_[p] = (s0) + 2; ++p; }              \
            if (m3) { if (p < LCAP) list_[p] = (s0) + 3; ++p; }              \
        }                                                                    \
    }

    if (lab_stride == 2) {            // int64 labels: int4 = 2 labels (x,z low)
        const int4* lab4 = (const int4*)labels;
        for (int iter = 0; iter < 16; ++iter) {
            int chunk = iter * NW + w;           // 0..255 chunks of 256 samples
            int s0 = chunk * 256 + lane * 4;
            int4 v0 = lab4[(s0 >> 1)];
            int4 v1 = lab4[(s0 >> 1) + 1];
            COMPACT4(v0.x == c, v0.z == c, v1.x == c, v1.z == c, s0);
        }
    } else {                          // int32 labels: int4 = 4 labels
        const int4* lab4 = (const int4*)labels;
        for (int iter = 0; iter < 16; ++iter) {
            int chunk = iter * NW + w;
            int s0 = chunk * 256 + lane * 4;
            int4 v = lab4[s0 >> 2];
            COMPACT4(v.x == c, v.y == c, v.z == c, v.w == c, s0);
        }
    }
#undef COMPACT4
    __syncthreads();
    const int cnt = (s_cnt > LCAP) ? LCAP : s_cnt;

    // ---------------- B: stream feature rows (R10 depth-2 rotation) ---------
    float4 ck[4];
#pragma unroll
    for (int j = 0; j < 4; ++j) ck[j] = cc4[j * 64 + lane];

    float4 dsum[4];
#pragma unroll
    for (int j = 0; j < 4; ++j) dsum[j] = make_float4(0.f, 0.f, 0.f, 0.f);

    int niter = (cnt > w) ? ((cnt - w - 1) / NW + 1) : 0;   // wave w: w, w+16, ...

#define LOADROW(buf, idx)                                                    \
    {                                                                        \
        const float4* f_ = (const float4*)(features + (size_t)(idx) * D_DIM);\
        _Pragma("unroll")                                                    \
        for (int j = 0; j < 4; ++j) buf[j] = f_[j * 64 + lane];              \
    }
#define COMPUTE(buf, pos)                                                    \
    {                                                                        \
        float nume = 0.f;                                                    \
        _Pragma("unroll")                                                    \
        for (int j = 0; j < 4; ++j) {                                        \
            float dx = buf[j].x - ck[j].x, dy = buf[j].y - ck[j].y;          \
            float dz = buf[j].z - ck[j].z, dw = buf[j].w - ck[j].w;          \
            dsum[j].x += dx; dsum[j].y += dy;                                \
            dsum[j].z += dz; dsum[j].w += dw;                                \
            nume += dx * dx + dy * dy + dz * dz + dw * dw;                   \
        }                                                                    \
        _Pragma("unroll")                                                    \
        for (int m = 32; m >= 1; m >>= 1) nume += __shfl_xor(nume, m, 64);   \
        if (lane == 0) nume_lds[pos] = nume;                                 \
    }

    float4 bufA[4], bufB[4];
    int ia = (0 < niter) ? list_[w] : -1;
    int ib = (1 < niter) ? list_[w + NW] : -1;
    if (ia >= 0) LOADROW(bufA, ia);
    int n = 0;
    while (n + 1 < niter) {
        LOADROW(bufB, ib);                                   // prefetch n+1
        int ic = (n + 2 < niter) ? list_[w + (n + 2) * NW] : -1;
        COMPUTE(bufA, w + n * NW);                           // compute n
        if (ic >= 0) LOADROW(bufA, ic);                      // prefetch n+2
        int id = (n + 3 < niter) ? list_[w + (n + 3) * NW] : -1;
        COMPUTE(bufB, w + (n + 1) * NW);                     // compute n+1
        ia = ic; ib = id; n += 2;
    }
    if (n < niter) COMPUTE(bufA, w + n * NW);                // odd tail
#undef LOADROW
#undef COMPUTE

    // park dsum in LDS (read only after the barrier below)
    {
        float4* cwv = (float4*)comb[w];
#pragma unroll
        for (int j = 0; j < 4; ++j) cwv[j * 64 + lane] = dsum[j];
    }

    // ---------------- C: per-wave denom tail (no barrier before) ------------
    // T += my 16 cluster rows; ssq += their squares. Relu-free algebra
    // (validated R12): denom = 256*||c_c||^2 + S - 2*c_c.T + alpha.
    {
        float4 tsum[4];
#pragma unroll
        for (int j = 0; j < 4; ++j) tsum[j] = make_float4(0.f, 0.f, 0.f, 0.f);
        float ssq = 0.f;
        for (int r = w; r < C_CLASSES; r += NW) {
            const float4* row = (const float4*)(cluster + (size_t)r * D_DIM);
#pragma unroll
            for (int j = 0; j < 4; ++j) {
                float4 v = row[j * 64 + lane];
                tsum[j].x += v.x; tsum[j].y += v.y;
                tsum[j].z += v.z; tsum[j].w += v.w;
                ssq += v.x * v.x + v.y * v.y + v.z * v.z + v.w * v.w;
            }
        }
#pragma unroll
        for (int j = 0; j < 4; ++j) {
            int d = 4 * (j * 64 + lane);
            atomicAdd(&Tlds[d + 0], tsum[j].x);
            atomicAdd(&Tlds[d + 1], tsum[j].y);
            atomicAdd(&Tlds[d + 2], tsum[j].z);
            atomicAdd(&Tlds[d + 3], tsum[j].w);
        }
#pragma unroll
        for (int m = 32; m >= 1; m >>= 1) ssq += __shfl_xor(ssq, m, 64);
        if (lane == 0) atomicAdd(&s_S, ssq);
    }
    __syncthreads();   // the single mid-kernel barrier

    // ---------------- D: finish -------------------------------------------
    if (t < 64) {
        const float4* T4 = (const float4*)Tlds;
        float dt = 0.f, sqc = 0.f;
#pragma unroll
        for (int j = 0; j < 4; ++j) {
            float4 tv = T4[j * 64 + lane];
            float4 av = cc4[j * 64 + lane];
            dt  += tv.x * av.x + tv.y * av.y + tv.z * av.z + tv.w * av.w;
            sqc += av.x * av.x + av.y * av.y + av.z * av.z + av.w * av.w;
        }
#pragma unroll
        for (int m = 32; m >= 1; m >>= 1) {
            dt  += __shfl_xor(dt,  m, 64);
            sqc += __shfl_xor(sqc, m, 64);
        }
        if (lane == 0)
            s_denom = 256.f * sqc + s_S - 2.f * dt + ALPHA_C;
    }
    __syncthreads();
    const float inv_dnm = 1.0f / s_denom;

    for (int j = t; j < cnt; j += 1024)
        loss_out[list_[j]] = nume_lds[j] * inv_dnm;

    if (t < 256) {
        float sc_ = GAMMA_C * cls_w[c] * inv_dnm;
        float4 s = make_float4(0.f, 0.f, 0.f, 0.f);
#pragma unroll
        for (int r = 0; r < NW; ++r) {
            float4 u = ((const float4*)comb[r])[t];
            s.x += u.x; s.y += u.y; s.z += u.z; s.w += u.w;
        }
        float4 cv = cc4[t];
        float4 o;
        o.x = cv.x - sc_ * s.x;
        o.y = cv.y - sc_ * s.y;
        o.z = cv.z - sc_ * s.z;
        o.w = cv.w - sc_ * s.w;
        ((float4*)(out_cluster + (size_t)c * D_DIM))[t] = o;
    }
}

// ---------------------------------------------------------------------------
extern "C" void kernel_launch(void* const* d_in, const int* in_sizes, int n_in,
                              void* d_out, int out_size, void* d_ws, size_t ws_size,
                              hipStream_t stream) {
    const float* features = (const float*)d_in[0];
    const int*   labels   = (const int*)d_in[1];
    const float* cluster  = (const float*)d_in[2];
    const float* cls_w    = (const float*)d_in[3];
    int lab_stride = in_sizes[1] / N_SAMPLES;   // 1 if int32 words, 2 if int64 words
    if (lab_stride < 1) lab_stride = 1;

    float* loss_out    = (float*)d_out;                 // N floats
    float* out_cluster = (float*)d_out + N_SAMPLES;     // C*D floats

    fused_kernel<<<C_CLASSES, 1024, 0, stream>>>(features, labels, lab_stride,
                                                 cluster, cls_w, loss_out, out_cluster);
}

// Round 15
// 61.508 us; speedup vs baseline: 3.2463x; 1.2769x over previous
//
#include <hip/hip_runtime.h>

#define N_SAMPLES 65536
#define C_CLASSES 256
#define D_DIM     1024
#define ALPHA_C   1.0f
#define GAMMA_C   0.01f
#define LCAP      1024     // per-class index list capacity (mean 256, sd 16)
#define NW        16       // waves per block (1024 threads)

// One block per class, 1024 threads (16 waves), single dispatch.
// R10 structure with phases A (label compaction) and B (denom sq/dot rows)
// MERGED into one 16-iteration loop: both are independent L2-bound phases,
// so interleaving their loads + DS chains hides their latencies mutually.
// Everything else (stream with direct loss stores, depth-2 rotation, combine)
// is byte-identical to the 65.5 us R10 kernel.
__global__ __launch_bounds__(1024, 1) void fused_kernel(
    const float* __restrict__ features,
    const int*   __restrict__ labels, int lab_stride,
    const float* __restrict__ cluster,
    const float* __restrict__ cls_w,
    float* __restrict__ loss_out,
    float* __restrict__ out_cluster)
{
    __shared__ int   list_[LCAP];                  // 4 KB
    __shared__ int   s_cnt;
    __shared__ float s_denom;
    __shared__ alignas(16) float cc[D_DIM];        // 4 KB (my cluster row)
    __shared__ float sqv[C_CLASSES];               // 1 KB
    __shared__ float dotv[C_CLASSES];              // 1 KB
    __shared__ alignas(16) float comb[NW][D_DIM];  // 64 KB (wave dsum combine)

    const int c = blockIdx.x;
    const int t = threadIdx.x;
    const int w = t >> 6, lane = t & 63;

    if (t == 0) s_cnt = 0;
    if (t < 256) ((float4*)cc)[t] = ((const float4*)(cluster + (size_t)c * D_DIM))[t];
    __syncthreads();
    const float4* cc4 = (const float4*)cc;

    // ------- A+B merged: compaction chunk i  ||  denom row i, 16 iters ------
#define BALLOT_SCATTER(m0, m1, m2, m3, s0)                                   \
    {                                                                        \
        unsigned long long b0 = __ballot(m0), b1 = __ballot(m1);             \
        unsigned long long b2 = __ballot(m2), b3 = __ballot(m3);             \
        int tot = __popcll(b0) + __popcll(b1) + __popcll(b2) + __popcll(b3); \
        if (tot) {                                                           \
            int bb = 0;                                                      \
            if (lane == 0) bb = atomicAdd(&s_cnt, tot);                      \
            bb = __shfl(bb, 0, 64);                                          \
            unsigned long long lm = (1ull << lane) - 1ull;                   \
            int p = bb + __popcll(b0 & lm) + __popcll(b1 & lm)               \
                       + __popcll(b2 & lm) + __popcll(b3 & lm);              \
            if (m0) { if (p < LCAP) list_[p] = (s0);     ++p; }              \
            if (m1) { if (p < LCAP) list_[p] = (s0) + 1; ++p; }              \
            if (m2) { if (p < LCAP) list_[p] = (s0) + 2; ++p; }              \
            if (m3) { if (p < LCAP) list_[p] = (s0) + 3; ++p; }              \
        }                                                                    \
    }
#define DENOM_ROW(r, rv)                                                     \
    {                                                                        \
        float sq = 0.f, dt = 0.f;                                            \
        _Pragma("unroll")                                                    \
        for (int j = 0; j < 4; ++j) {                                        \
            float4 a = cc4[j * 64 + lane];                                   \
            sq += rv[j].x * rv[j].x + rv[j].y * rv[j].y +                    \
                  rv[j].z * rv[j].z + rv[j].w * rv[j].w;                     \
            dt += rv[j].x * a.x + rv[j].y * a.y +                            \
                  rv[j].z * a.z + rv[j].w * a.w;                             \
        }                                                                    \
        _Pragma("unroll")                                                    \
        for (int m = 32; m >= 1; m >>= 1) {                                  \
            sq += __shfl_xor(sq, m, 64);                                     \
            dt += __shfl_xor(dt, m, 64);                                     \
        }                                                                    \
        if (lane == 0) { sqv[r] = sq; dotv[r] = dt; }                        \
    }

    if (lab_stride == 2) {            // int64 labels: int4 = 2 labels (x,z low)
        const int4* lab4 = (const int4*)labels;
        for (int iter = 0; iter < 16; ++iter) {
            int idx = iter * NW + w;             // chunk id AND row id, 0..255
            int s0 = idx * 256 + lane * 4;
            // issue both load streams up front (independent)
            int4 v0 = lab4[(s0 >> 1)];
            int4 v1 = lab4[(s0 >> 1) + 1];
            const float4* row = (const float4*)(cluster + (size_t)idx * D_DIM);
            float4 rv[4];
#pragma unroll
            for (int j = 0; j < 4; ++j) rv[j] = row[j * 64 + lane];
            BALLOT_SCATTER(v0.x == c, v0.z == c, v1.x == c, v1.z == c, s0);
            DENOM_ROW(idx, rv);
        }
    } else {                          // int32 labels: int4 = 4 labels
        const int4* lab4 = (const int4*)labels;
        for (int iter = 0; iter < 16; ++iter) {
            int idx = iter * NW + w;
            int s0 = idx * 256 + lane * 4;
            int4 v = lab4[s0 >> 2];
            const float4* row = (const float4*)(cluster + (size_t)idx * D_DIM);
            float4 rv[4];
#pragma unroll
            for (int j = 0; j < 4; ++j) rv[j] = row[j * 64 + lane];
            BALLOT_SCATTER(v.x == c, v.y == c, v.z == c, v.w == c, s0);
            DENOM_ROW(idx, rv);
        }
    }
#undef BALLOT_SCATTER
#undef DENOM_ROW
    __syncthreads();
    const int cnt = (s_cnt > LCAP) ? LCAP : s_cnt;

    // ---------------- denom finish (64 lanes) -------------------------------
    if (t < 64) {
        float sqc = sqv[c];
        float s = 0.f;
#pragma unroll
        for (int jj = 0; jj < 4; ++jj) {
            int j = jj * 64 + lane;
            float p = sqc + sqv[j] - 2.f * dotv[j];
            s += (p > 0.f ? p : 0.f);
        }
#pragma unroll
        for (int m = 32; m >= 1; m >>= 1) s += __shfl_xor(s, m, 64);
        if (lane == 0) s_denom = s + ALPHA_C;
    }
    __syncthreads();
    const float inv_dnm = 1.0f / s_denom;

    // ---------------- stream feature rows (R10 depth-2 rotation) ------------
    float4 ck[4];
#pragma unroll
    for (int j = 0; j < 4; ++j) ck[j] = cc4[j * 64 + lane];

    float4 dsum[4];
#pragma unroll
    for (int j = 0; j < 4; ++j) dsum[j] = make_float4(0.f, 0.f, 0.f, 0.f);

    int niter = (cnt > w) ? ((cnt - w - 1) / NW + 1) : 0;   // wave w: w, w+16, ...

#define LOADROW(buf, idx)                                                    \
    {                                                                        \
        const float4* f_ = (const float4*)(features + (size_t)(idx) * D_DIM);\
        _Pragma("unroll")                                                    \
        for (int j = 0; j < 4; ++j) buf[j] = f_[j * 64 + lane];              \
    }
#define COMPUTE(buf, idx)                                                    \
    {                                                                        \
        float nume = 0.f;                                                    \
        _Pragma("unroll")                                                    \
        for (int j = 0; j < 4; ++j) {                                        \
            float dx = buf[j].x - ck[j].x, dy = buf[j].y - ck[j].y;          \
            float dz = buf[j].z - ck[j].z, dw = buf[j].w - ck[j].w;          \
            dsum[j].x += dx; dsum[j].y += dy;                                \
            dsum[j].z += dz; dsum[j].w += dw;                                \
            nume += dx * dx + dy * dy + dz * dz + dw * dw;                   \
        }                                                                    \
        _Pragma("unroll")                                                    \
        for (int m = 32; m >= 1; m >>= 1) nume += __shfl_xor(nume, m, 64);   \
        if (lane == 0) loss_out[idx] = nume * inv_dnm;                       \
    }

    float4 bufA[4], bufB[4];
    int ia = (0 < niter) ? list_[w] : -1;
    int ib = (1 < niter) ? list_[w + NW] : -1;
    if (ia >= 0) LOADROW(bufA, ia);
    int n = 0;
    while (n + 1 < niter) {
        LOADROW(bufB, ib);                                   // prefetch n+1
        int ic = (n + 2 < niter) ? list_[w + (n + 2) * NW] : -1;
        COMPUTE(bufA, ia);                                   // compute n
        if (ic >= 0) LOADROW(bufA, ic);                      // prefetch n+2
        int id = (n + 3 < niter) ? list_[w + (n + 3) * NW] : -1;
        COMPUTE(bufB, ib);                                   // compute n+1
        ia = ic; ib = id; n += 2;
    }
    if (n < niter) COMPUTE(bufA, ia);                        // odd tail
#undef LOADROW
#undef COMPUTE

    // ---------------- combine dsum across 16 waves, direct store ------------
    {
        float4* cwv = (float4*)comb[w];
#pragma unroll
        for (int j = 0; j < 4; ++j) cwv[j * 64 + lane] = dsum[j];
    }
    __syncthreads();
    if (t < 256) {
        float sc_ = GAMMA_C * cls_w[c] * inv_dnm;
        float4 s = make_float4(0.f, 0.f, 0.f, 0.f);
#pragma unroll
        for (int r = 0; r < NW; ++r) {
            float4 u = ((const float4*)comb[r])[t];
            s.x += u.x; s.y += u.y; s.z += u.z; s.w += u.w;
        }
        float4 cv = cc4[t];
        float4 o;
        o.x = cv.x - sc_ * s.x;
        o.y = cv.y - sc_ * s.y;
        o.z = cv.z - sc_ * s.z;
        o.w = cv.w - sc_ * s.w;
        ((float4*)(out_cluster + (size_t)c * D_DIM))[t] = o;
    }
}

// ---------------------------------------------------------------------------
extern "C" void kernel_launch(void* const* d_in, const int* in_sizes, int n_in,
                              void* d_out, int out_size, void* d_ws, size_t ws_size,
                              hipStream_t stream) {
    const float* features = (const float*)d_in[0];
    const int*   labels   = (const int*)d_in[1];
    const float* cluster  = (const float*)d_in[2];
    const float* cls_w    = (const float*)d_in[3];
    int lab_stride = in_sizes[1] / N_SAMPLES;   // 1 if int32 words, 2 if int64 words
    if (lab_stride < 1) lab_stride = 1;

    float* loss_out    = (float*)d_out;                 // N floats
    float* out_cluster = (float*)d_out + N_SAMPLES;     // C*D floats

    fused_kernel<<<C_CLASSES, 1024, 0, stream>>>(features, labels, lab_stride,
                                                 cluster, cls_w, loss_out, out_cluster);
}